// Round 5
// baseline (427.661 us; speedup 1.0000x reference)
//
#include <hip/hip_runtime.h>

typedef unsigned short u16;
typedef unsigned int   u32;
typedef unsigned char  u8;

using bf16x8 = __attribute__((ext_vector_type(8))) __bf16;
using f32x4  = __attribute__((ext_vector_type(4))) float;
using s16x4  = __attribute__((ext_vector_type(4))) short;

__device__ __forceinline__ u16 f2bf(float f) {
    u32 u = __float_as_uint(f);
    return (u16)((u + 0x7FFFu + ((u >> 16) & 1u)) >> 16);
}

#define MFMA(a, b, c) __builtin_amdgcn_mfma_f32_16x16x32_bf16((a), (b), (c), 0, 0, 0)
#define MFMA16(a, b, c) __builtin_amdgcn_mfma_f32_16x16x16bf16_1k((a), (b), (c), 0, 0, 0)

// async global->LDS 16B: per-lane global source, wave-uniform LDS base + lane*16
__device__ __forceinline__ void gll16(const u16* g, u16* l) {
    __builtin_amdgcn_global_load_lds(
        (const __attribute__((address_space(1))) void*)g,
        (__attribute__((address_space(3))) void*)l, 16, 0, 0);
}

// ---------------------------------------------------------------------------
// Wt[n][k] = bf16(W[k][n]) for 4 weights in one launch. N = K = 1280.
// ---------------------------------------------------------------------------
__global__ __launch_bounds__(256) void wtrans_kernel(
    const float* __restrict__ W0, const float* __restrict__ W1,
    const float* __restrict__ W2, const float* __restrict__ W3,
    u16* __restrict__ T0, u16* __restrict__ T1,
    u16* __restrict__ T2, u16* __restrict__ T3) {
    const int N = 1280;
    const int z = blockIdx.z;
    const float* W = (z == 0) ? W0 : (z == 1) ? W1 : (z == 2) ? W2 : W3;
    u16* T = (z == 0) ? T0 : (z == 1) ? T1 : (z == 2) ? T2 : T3;
    __shared__ float t[32][33];
    const int bx = blockIdx.x * 32, by = blockIdx.y * 32;
    const int x = threadIdx.x, ty = threadIdx.y;
#pragma unroll
    for (int j = 0; j < 4; j++) {
        const int y = ty + j * 8;
        t[y][x] = W[(size_t)(by + y) * N + (bx + x)];
    }
    __syncthreads();
#pragma unroll
    for (int j = 0; j < 4; j++) {
        const int y = ty + j * 8;
        T[(size_t)(bx + y) * N + (by + x)] = f2bf(t[x][y]);
    }
}

// ---------------------------------------------------------------------------
// fp32 -> bf16 convert, 8 elems/thread
// ---------------------------------------------------------------------------
__global__ __launch_bounds__(256) void conv_kernel(const float* __restrict__ in,
                                                   u16* __restrict__ out, int n8) {
    const int i = blockIdx.x * 256 + threadIdx.x;
    if (i >= n8) return;
    const float4 a = ((const float4*)in)[i * 2];
    const float4 b = ((const float4*)in)[i * 2 + 1];
    union { uint4 u; u16 s[8]; } cv;
    cv.s[0] = f2bf(a.x); cv.s[1] = f2bf(a.y); cv.s[2] = f2bf(a.z); cv.s[3] = f2bf(a.w);
    cv.s[4] = f2bf(b.x); cv.s[5] = f2bf(b.y); cv.s[6] = f2bf(b.z); cv.s[7] = f2bf(b.w);
    ((uint4*)out)[i] = cv.u;
}

// ---------------------------------------------------------------------------
// C[M,N] = A[M,K] @ Bt[N,K]^T, bf16 in. m97-structure: global_load_lds into
// linear LDS, pre-swizzled source chunk (^= row&7), swizzled ds_read_b128,
// double-buffered, one vmcnt(0)+barrier per K-tile. BM=MI*32, BN=128.
// ---------------------------------------------------------------------------
template <int MI, bool TRANSC, bool EPI>
__global__ __launch_bounds__(256) void gemm2_kernel(
    const u16* __restrict__ A, const u16* __restrict__ Bt, void* __restrict__ Cp,
    const float* __restrict__ bias, const float* __restrict__ resid,
    const int M, const int N, const int K) {
    __shared__ __align__(16) u16 Al[2][MI * 32 * 64];
    __shared__ __align__(16) u16 Bl[2][128 * 64];
    const int tid = threadIdx.x;
    const int lane = tid & 63, w = tid >> 6;
    const int wr = w >> 1, wc = w & 1;
    const int lr = lane & 15, lq = lane >> 4;
    const int m0 = blockIdx.y * (MI * 32), n0 = blockIdx.x * 128;

    const int f_r = tid >> 3;                       // row within 32-row pass
    const int srcch = (tid & 7) ^ ((tid >> 3) & 7); // swizzled source chunk
    const int ldst = (tid & 192) * 8;               // wave-uniform LDS u16 base

    const f32x4 fzero = {0.f, 0.f, 0.f, 0.f};
    f32x4 acc[MI][4];
#pragma unroll
    for (int i = 0; i < MI; i++)
#pragma unroll
        for (int j = 0; j < 4; j++) acc[i][j] = fzero;

    const int nkt = K >> 6;

#define STAGE(buf, kt)                                                          \
    {                                                                           \
        const int k0s = (kt) << 6;                                              \
        _Pragma("unroll")                                                       \
        for (int i = 0; i < MI; i++) {                                          \
            const int r = i * 32 + f_r;                                         \
            gll16(&A[(size_t)(m0 + r) * K + k0s + srcch * 8],                   \
                  &Al[buf][i * 2048 + ldst]);                                   \
        }                                                                       \
        _Pragma("unroll")                                                       \
        for (int i = 0; i < 4; i++) {                                           \
            const int r = i * 32 + f_r;                                         \
            gll16(&Bt[(size_t)(n0 + r) * K + k0s + srcch * 8],                  \
                  &Bl[buf][i * 2048 + ldst]);                                   \
        }                                                                       \
    }

    STAGE(0, 0);
    asm volatile("s_waitcnt vmcnt(0)" ::: "memory");
    __syncthreads();
    int cur = 0;
    for (int kt = 0; kt < nkt; kt++) {
        if (kt + 1 < nkt) STAGE(cur ^ 1, kt + 1);
#pragma unroll
        for (int ks = 0; ks < 2; ks++) {
            bf16x8 af[MI], bfv[4];
#pragma unroll
            for (int mi = 0; mi < MI; mi++) {
                const int rowA = wr * (MI * 16) + mi * 16 + lr;
                af[mi] = *(const bf16x8*)&Al[cur][rowA * 64 +
                                                  (((ks * 4 + lq) ^ (rowA & 7)) << 3)];
            }
#pragma unroll
            for (int ni = 0; ni < 4; ni++) {
                const int rowB = wc * 64 + ni * 16 + lr;
                bfv[ni] = *(const bf16x8*)&Bl[cur][rowB * 64 +
                                                   (((ks * 4 + lq) ^ (rowB & 7)) << 3)];
            }
#pragma unroll
            for (int mi = 0; mi < MI; mi++)
#pragma unroll
                for (int ni = 0; ni < 4; ni++)
                    acc[mi][ni] = MFMA(af[mi], bfv[ni], acc[mi][ni]);
        }
        asm volatile("s_waitcnt vmcnt(0)" ::: "memory");
        __syncthreads();
        cur ^= 1;
    }
#undef STAGE

#pragma unroll
    for (int mi = 0; mi < MI; mi++)
#pragma unroll
        for (int ni = 0; ni < 4; ni++)
#pragma unroll
            for (int j = 0; j < 4; j++) {
                const int row = m0 + wr * (MI * 16) + mi * 16 + lq * 4 + j;
                const int col = n0 + wc * 64 + ni * 16 + lr;
                const float v = acc[mi][ni][j];
                if (EPI) {
                    ((float*)Cp)[(size_t)row * N + col] =
                        v + bias[col] + resid[(size_t)row * N + col];
                } else if (TRANSC) {
                    ((u16*)Cp)[((size_t)(col >> 11) * 1280 + row) * 2048 +
                               (col & 2047)] = f2bf(v);
                } else {
                    ((u16*)Cp)[(size_t)row * N + col] = f2bf(v);
                }
            }
}

// ---------------------------------------------------------------------------
// Flash attention. Grid 512 (id = qt*16 + bz*8 + h; same-h blocks share XCD
// L2 for K/V). Block 512 thr = 8 waves = 2 q-groups x 4 key-columns.
// 32 q-rows/block; shared 64-key K/V tile staged in LDS (coalesced,
// reg-prefetched one tile ahead). Wave (qg,kc): 16 q-rows x 16 keys,
// private online softmax (defer-max via __any on unreduced scores; row-sum l
// via ones-column MFMA). PV with 16x16x16 MFMA. In-LDS end merge.
// ---------------------------------------------------------------------------
__global__ __launch_bounds__(512, 4) void attn_kernel(
    const u16* __restrict__ qb, const u16* __restrict__ kb,
    const u16* __restrict__ vtb, const int* __restrict__ seg,
    u16* __restrict__ ao) {
    __shared__ __align__(16) u16 arena[29504];
    const int KL = 0;       // K  [64][168] u16        (10752)
    const int VT = 10752;   // Vt [160][88] u16        (14080)
    const int PT = 24832;   // P   8 x [16][24] u16    (3072)
    const int SG = 27904;   // seg u8[8][256]          (1024 u16)
    const int MLO = 28928;  // f32 [8][16][2]          (512 u16)
    const int LIO = 29440;  // f32 [32]                (64 u16)
    u8* segl8 = (u8*)&arena[SG];
    float* Mlf = (float*)&arena[MLO];
    float* Linv = (float*)&arena[LIO];
    float* Osum = (float*)&arena[KL];  // overlay [2][16][168] f32 = 10752 u16

    const int tid = threadIdx.x;
    const int lane = tid & 63, w = tid >> 6;
    const int qg = w >> 2, kc = w & 3;
    const int lr = lane & 15, lq = lane >> 4;
    const int id = blockIdx.x;
    const int h = id & 7, bz = (id >> 3) & 1, qt = id >> 4;  // qt 0..31

    // seg rows qt*8..+8 (one int4 = 4 flags per thread)
    {
        const int4 v = *(const int4*)&seg[(size_t)(bz * 256 + qt * 8) * 256 + tid * 4];
        segl8[tid * 4 + 0] = (u8)v.x; segl8[tid * 4 + 1] = (u8)v.y;
        segl8[tid * 4 + 2] = (u8)v.z; segl8[tid * 4 + 3] = (u8)v.w;
    }

    // Q fragments
    bf16x8 qf[5];
    {
        const size_t qrow =
            (size_t)(bz * 1024 + qt * 32 + qg * 16 + lr) * 1280 + h * 160;
#pragma unroll
        for (int ks = 0; ks < 5; ks++)
            qf[ks] = *(const bf16x8*)&qb[qrow + ks * 32 + lq * 8];
    }

    // staging geometry: K flat n -> row=n/20,c8=n%20 ; V flat n -> d=n>>3,c8=n&7
    const bool xK = (tid < 256);
    const int nK0 = tid, nK1 = tid + 512, nV0 = tid, nV1 = tid + 512;
    const int nX = xK ? (1024 + tid) : (768 + tid);
    const int klo0 = (nK0 / 20) * 168 + (nK0 % 20) * 8;
    const int kgo0 = (nK0 / 20) * 1280 + (nK0 % 20) * 8;
    const int klo1 = (nK1 / 20) * 168 + (nK1 % 20) * 8;
    const int kgo1 = (nK1 / 20) * 1280 + (nK1 % 20) * 8;
    const int vlo0 = (nV0 >> 3) * 88 + (nV0 & 7) * 8;
    const int vgo0 = (nV0 >> 3) * 2048 + (nV0 & 7) * 8;
    const int vlo1 = (nV1 >> 3) * 88 + (nV1 & 7) * 8;
    const int vgo1 = (nV1 >> 3) * 2048 + (nV1 & 7) * 8;
    const int xlo = xK ? ((nX / 20) * 168 + (nX % 20) * 8)
                       : ((nX >> 3) * 88 + (nX & 7) * 8);
    const int xgo = xK ? ((nX / 20) * 1280 + (nX % 20) * 8)
                       : ((nX >> 3) * 2048 + (nX & 7) * 8);

    const u16* kT0 = kb + (size_t)(bz * 2048) * 1280 + h * 160;   // + kt*64*1280
    const u16* vT0 = vtb + (size_t)(bz * 1280 + h * 160) * 2048;  // + kt*64

    const f32x4 fzero = {0.f, 0.f, 0.f, 0.f};
    f32x4 oacc[10];
#pragma unroll
    for (int d = 0; d < 10; d++) oacc[d] = fzero;
    f32x4 oaccL = fzero;
    float m_i[4] = {0.f, 0.f, 0.f, 0.f};
    const float sc = 0.07905694150420949f;  // 1/sqrt(160)
    const s16x4 ones = {(short)0x3F80, (short)0x3F80, (short)0x3F80, (short)0x3F80};

    uint4 k0r, k1r, v0r, v1r, xr;
    k0r = *(const uint4*)&kT0[kgo0];
    k1r = *(const uint4*)&kT0[kgo1];
    v0r = *(const uint4*)&vT0[vgo0];
    v1r = *(const uint4*)&vT0[vgo1];
    xr = xK ? *(const uint4*)&kT0[xgo] : *(const uint4*)&vT0[xgo];

    for (int kt = 0; kt < 32; kt++) {
        __syncthreads();  // everyone done reading prev tile (t=0: segl ready after)
        *(uint4*)&arena[KL + klo0] = k0r;
        *(uint4*)&arena[KL + klo1] = k1r;
        *(uint4*)&arena[VT + vlo0] = v0r;
        *(uint4*)&arena[VT + vlo1] = v1r;
        if (xK) *(uint4*)&arena[KL + xlo] = xr;
        else    *(uint4*)&arena[VT + xlo] = xr;
        if (kt + 1 < 32) {
            const u16* kT = kT0 + (size_t)(kt + 1) * 64 * 1280;
            const u16* vT = vT0 + (kt + 1) * 64;
            k0r = *(const uint4*)&kT[kgo0];
            k1r = *(const uint4*)&kT[kgo1];
            v0r = *(const uint4*)&vT[vgo0];
            v1r = *(const uint4*)&vT[vgo1];
            xr = xK ? *(const uint4*)&kT[xgo] : *(const uint4*)&vT[xgo];
        }
        __syncthreads();  // tile visible

        // --- QK^T: 16 q-rows x 16 keys (this wave's column) ---
        f32x4 s4 = fzero;
#pragma unroll
        for (int ks = 0; ks < 5; ks++) {
            const bf16x8 bk =
                *(const bf16x8*)&arena[KL + (kc * 16 + lr) * 168 + ks * 32 + lq * 8];
            s4 = MFMA(qf[ks], bk, s4);
        }
        float msk = 0.f;
        if (kt >= 16)
            msk = segl8[(qg * 4 + lq) * 256 + (kt - 16) * 16 + kc * 4 + (lr >> 2)]
                      ? 0.f : -1e30f;
#pragma unroll
        for (int j = 0; j < 4; j++) s4[j] = s4[j] * sc + msk;

        // defer-max: check on unreduced scores (THR=8); rescale branch ~never
        const bool ex = (s4[0] > m_i[0] + 8.f) || (s4[1] > m_i[1] + 8.f) ||
                        (s4[2] > m_i[2] + 8.f) || (s4[3] > m_i[3] + 8.f);
        if (__any(ex)) {
#pragma unroll
            for (int j = 0; j < 4; j++) {
                float rm = s4[j];
                rm = fmaxf(rm, __shfl_xor(rm, 1));
                rm = fmaxf(rm, __shfl_xor(rm, 2));
                rm = fmaxf(rm, __shfl_xor(rm, 4));
                rm = fmaxf(rm, __shfl_xor(rm, 8));
                const float mn = fmaxf(m_i[j], rm);
                const float al = __expf(m_i[j] - mn);
#pragma unroll
                for (int d = 0; d < 10; d++) oacc[d][j] *= al;
                oaccL[j] *= al;
                m_i[j] = mn;
            }
        }
        // exp + P -> wave-private LDS (Pt[q][k])
        u16* ptw = &arena[PT + w * 384];
#pragma unroll
        for (int j = 0; j < 4; j++) {
            const float e = __expf(s4[j] - m_i[j]);
            ptw[(lq * 4 + j) * 24 + lr] = f2bf(e);
        }
        // A-frag (same-wave DS order guarantees visibility)
        const s16x4 pa = *(const s16x4*)&ptw[lr * 24 + lq * 4];
        oaccL = MFMA16(pa, ones, oaccL);  // row-sum l
#pragma unroll
        for (int nt2 = 0; nt2 < 10; nt2++) {
            const s16x4 bv =
                *(const s16x4*)&arena[VT + (nt2 * 16 + lr) * 88 + kc * 16 + lq * 4];
            oacc[nt2] = MFMA16(pa, bv, oacc[nt2]);
        }
    }

    // ---- merge 4 key-column partials per q-group (in LDS) ----
    if (lr == 0) {
#pragma unroll
        for (int j = 0; j < 4; j++) {
            Mlf[(w * 16 + lq * 4 + j) * 2 + 0] = m_i[j];
            Mlf[(w * 16 + lq * 4 + j) * 2 + 1] = oaccL[j];
        }
    }
    __syncthreads();
    for (int e = tid; e < 5376; e += 512) Osum[e] = 0.f;
    float aj[4];
#pragma unroll
    for (int j = 0; j < 4; j++) {
        const int row = lq * 4 + j;
        float M = -1e30f;
#pragma unroll
        for (int k2 = 0; k2 < 4; k2++)
            M = fmaxf(M, Mlf[((qg * 4 + k2) * 16 + row) * 2]);
        float L = 0.f;
#pragma unroll
        for (int k2 = 0; k2 < 4; k2++)
            L += Mlf[((qg * 4 + k2) * 16 + row) * 2 + 1] *
                 __expf(Mlf[((qg * 4 + k2) * 16 + row) * 2] - M);
        aj[j] = __expf(m_i[j] - M);
        if (kc == 0 && lr == 0) Linv[qg * 16 + row] = 1.f / L;
    }
    __syncthreads();  // Osum zeroed + Linv visible
#pragma unroll
    for (int nt2 = 0; nt2 < 10; nt2++)
#pragma unroll
        for (int j = 0; j < 4; j++)
            atomicAdd(&Osum[(qg * 16 + lq * 4 + j) * 168 + nt2 * 16 + lr],
                      oacc[nt2][j] * aj[j]);
    __syncthreads();
    // cooperative write: 32 rows x 160 cols, u32-packed pairs
#pragma unroll
    for (int p = 0; p < 5; p++) {
        const int e2 = p * 512 + tid;  // 0..2559
        const int r = e2 / 80, cp = e2 % 80;
        const float iv = Linv[r];
        const float a0 = Osum[r * 168 + cp * 2] * iv;
        const float a1 = Osum[r * 168 + cp * 2 + 1] * iv;
        const u32 pk = (u32)f2bf(a0) | ((u32)f2bf(a1) << 16);
        *(u32*)&ao[(size_t)(bz * 1024 + qt * 32 + r) * 1280 + h * 160 + cp * 2] = pk;
    }
}

// ---------------------------------------------------------------------------
extern "C" void kernel_launch(void* const* d_in, const int* in_sizes, int n_in,
                              void* d_out, int out_size, void* d_ws, size_t ws_size,
                              hipStream_t stream) {
    const float* hs  = (const float*)d_in[0];
    const float* ehs = (const float*)d_in[1];
    const int*   seg = (const int*)d_in[2];
    const float* Wq  = (const float*)d_in[3];
    const float* Wk  = (const float*)d_in[4];
    const float* Wv  = (const float*)d_in[5];
    const float* Wo  = (const float*)d_in[6];
    const float* bo  = (const float*)d_in[7];
    float* out = (float*)d_out;

    u16* base  = (u16*)d_ws;
    u16* WoT   = base;                  // 1,638,400
    u16* qbuf  = WoT + 1638400;         // 2,621,440
    u16* kbuf  = qbuf + 2621440;        // 5,242,880
    u16* vtbuf = kbuf + 5242880;        // 5,242,880
    u16* hbuf  = vtbuf + 5242880;       // 2,621,440 (= aobuf after attn)
    u16* ebuf  = hbuf + 2621440;        // 5,242,880
    u16* WqT   = ebuf + 5242880;        // 1,638,400
    u16* WkT   = WqT + 1638400;         // 1,638,400
    u16* WvT   = WkT + 1638400;         // 1,638,400
    u16* aobuf = hbuf;

    dim3 tb(32, 8), tg(40, 40, 4);
    wtrans_kernel<<<tg, tb, 0, stream>>>(Wq, Wk, Wv, Wo, WqT, WkT, WvT, WoT);
    conv_kernel<<<1280, 256, 0, stream>>>(hs, hbuf, 327680);
    conv_kernel<<<2560, 256, 0, stream>>>(ehs, ebuf, 655360);

    gemm2_kernel<2, false, false><<<dim3(10, 32), 256, 0, stream>>>(
        hbuf, WqT, qbuf, nullptr, nullptr, 2048, 1280, 1280);
    gemm2_kernel<4, false, false><<<dim3(10, 32), 256, 0, stream>>>(
        ebuf, WkT, kbuf, nullptr, nullptr, 4096, 1280, 1280);
    gemm2_kernel<4, true, false><<<dim3(32, 10), 256, 0, stream>>>(
        WvT, ebuf, vtbuf, nullptr, nullptr, 1280, 4096, 1280);

    attn_kernel<<<512, 512, 0, stream>>>(qbuf, kbuf, vtbuf, seg, aobuf);

    gemm2_kernel<2, false, true><<<dim3(10, 32), 256, 0, stream>>>(
        aobuf, WoT, out, bo, hs, 2048, 1280, 1280);
}

// Round 6
// 190.770 us; speedup vs baseline: 2.2418x; 2.2418x over previous
//
#include <hip/hip_runtime.h>

typedef unsigned short u16;
typedef unsigned int   u32;
typedef unsigned char  u8;

using bf16x8 = __attribute__((ext_vector_type(8))) __bf16;
using f32x4  = __attribute__((ext_vector_type(4))) float;
using s16x4  = __attribute__((ext_vector_type(4))) short;

__device__ __forceinline__ u16 f2bf(float f) {
    u32 u = __float_as_uint(f);
    return (u16)((u + 0x7FFFu + ((u >> 16) & 1u)) >> 16);
}

#define MFMA(a, b, c) __builtin_amdgcn_mfma_f32_16x16x32_bf16((a), (b), (c), 0, 0, 0)
#define MFMA16(a, b, c) __builtin_amdgcn_mfma_f32_16x16x16bf16_1k((a), (b), (c), 0, 0, 0)

// async global->LDS 16B: per-lane global source, wave-uniform LDS base + lane*16
__device__ __forceinline__ void gll16(const u16* g, u16* l) {
    __builtin_amdgcn_global_load_lds(
        (const __attribute__((address_space(1))) void*)g,
        (__attribute__((address_space(3))) void*)l, 16, 0, 0);
}

// ---------------------------------------------------------------------------
// Wt[n][k] = bf16(W[k][n]) for 4 weights in one launch. N = K = 1280.
// ---------------------------------------------------------------------------
__global__ __launch_bounds__(256) void wtrans_kernel(
    const float* __restrict__ W0, const float* __restrict__ W1,
    const float* __restrict__ W2, const float* __restrict__ W3,
    u16* __restrict__ T0, u16* __restrict__ T1,
    u16* __restrict__ T2, u16* __restrict__ T3) {
    const int N = 1280;
    const int z = blockIdx.z;
    const float* W = (z == 0) ? W0 : (z == 1) ? W1 : (z == 2) ? W2 : W3;
    u16* T = (z == 0) ? T0 : (z == 1) ? T1 : (z == 2) ? T2 : T3;
    __shared__ float t[32][33];
    const int bx = blockIdx.x * 32, by = blockIdx.y * 32;
    const int x = threadIdx.x, ty = threadIdx.y;
#pragma unroll
    for (int j = 0; j < 4; j++) {
        const int y = ty + j * 8;
        t[y][x] = W[(size_t)(by + y) * N + (bx + x)];
    }
    __syncthreads();
#pragma unroll
    for (int j = 0; j < 4; j++) {
        const int y = ty + j * 8;
        T[(size_t)(bx + y) * N + (by + x)] = f2bf(t[x][y]);
    }
}

// ---------------------------------------------------------------------------
// fp32 -> bf16 convert, 8 elems/thread
// ---------------------------------------------------------------------------
__global__ __launch_bounds__(256) void conv_kernel(const float* __restrict__ in,
                                                   u16* __restrict__ out, int n8) {
    const int i = blockIdx.x * 256 + threadIdx.x;
    if (i >= n8) return;
    const float4 a = ((const float4*)in)[i * 2];
    const float4 b = ((const float4*)in)[i * 2 + 1];
    union { uint4 u; u16 s[8]; } cv;
    cv.s[0] = f2bf(a.x); cv.s[1] = f2bf(a.y); cv.s[2] = f2bf(a.z); cv.s[3] = f2bf(a.w);
    cv.s[4] = f2bf(b.x); cv.s[5] = f2bf(b.y); cv.s[6] = f2bf(b.z); cv.s[7] = f2bf(b.w);
    ((uint4*)out)[i] = cv.u;
}

// ---------------------------------------------------------------------------
// C[M,N] = A[M,K] @ Bt[N,K]^T, bf16 in. m97-structure: global_load_lds into
// linear LDS, pre-swizzled source chunk (^= row&7), swizzled ds_read_b128,
// double-buffered, one vmcnt(0)+barrier per K-tile. BM=MI*32, BN=128.
// ---------------------------------------------------------------------------
template <int MI, bool TRANSC, bool EPI>
__global__ __launch_bounds__(256) void gemm2_kernel(
    const u16* __restrict__ A, const u16* __restrict__ Bt, void* __restrict__ Cp,
    const float* __restrict__ bias, const float* __restrict__ resid,
    const int M, const int N, const int K) {
    __shared__ __align__(16) u16 Al[2][MI * 32 * 64];
    __shared__ __align__(16) u16 Bl[2][128 * 64];
    const int tid = threadIdx.x;
    const int lane = tid & 63, w = tid >> 6;
    const int wr = w >> 1, wc = w & 1;
    const int lr = lane & 15, lq = lane >> 4;
    const int m0 = blockIdx.y * (MI * 32), n0 = blockIdx.x * 128;

    const int f_r = tid >> 3;                       // row within 32-row pass
    const int srcch = (tid & 7) ^ ((tid >> 3) & 7); // swizzled source chunk
    const int ldst = (tid & 192) * 8;               // wave-uniform LDS u16 base

    const f32x4 fzero = {0.f, 0.f, 0.f, 0.f};
    f32x4 acc[MI][4];
#pragma unroll
    for (int i = 0; i < MI; i++)
#pragma unroll
        for (int j = 0; j < 4; j++) acc[i][j] = fzero;

    const int nkt = K >> 6;

#define STAGE(buf, kt)                                                          \
    {                                                                           \
        const int k0s = (kt) << 6;                                              \
        _Pragma("unroll")                                                       \
        for (int i = 0; i < MI; i++) {                                          \
            const int r = i * 32 + f_r;                                         \
            gll16(&A[(size_t)(m0 + r) * K + k0s + srcch * 8],                   \
                  &Al[buf][i * 2048 + ldst]);                                   \
        }                                                                       \
        _Pragma("unroll")                                                       \
        for (int i = 0; i < 4; i++) {                                           \
            const int r = i * 32 + f_r;                                         \
            gll16(&Bt[(size_t)(n0 + r) * K + k0s + srcch * 8],                  \
                  &Bl[buf][i * 2048 + ldst]);                                   \
        }                                                                       \
    }

    STAGE(0, 0);
    asm volatile("s_waitcnt vmcnt(0)" ::: "memory");
    __syncthreads();
    int cur = 0;
    for (int kt = 0; kt < nkt; kt++) {
        if (kt + 1 < nkt) STAGE(cur ^ 1, kt + 1);
#pragma unroll
        for (int ks = 0; ks < 2; ks++) {
            bf16x8 af[MI], bfv[4];
#pragma unroll
            for (int mi = 0; mi < MI; mi++) {
                const int rowA = wr * (MI * 16) + mi * 16 + lr;
                af[mi] = *(const bf16x8*)&Al[cur][rowA * 64 +
                                                  (((ks * 4 + lq) ^ (rowA & 7)) << 3)];
            }
#pragma unroll
            for (int ni = 0; ni < 4; ni++) {
                const int rowB = wc * 64 + ni * 16 + lr;
                bfv[ni] = *(const bf16x8*)&Bl[cur][rowB * 64 +
                                                   (((ks * 4 + lq) ^ (rowB & 7)) << 3)];
            }
#pragma unroll
            for (int mi = 0; mi < MI; mi++)
#pragma unroll
                for (int ni = 0; ni < 4; ni++)
                    acc[mi][ni] = MFMA(af[mi], bfv[ni], acc[mi][ni]);
        }
        asm volatile("s_waitcnt vmcnt(0)" ::: "memory");
        __syncthreads();
        cur ^= 1;
    }
#undef STAGE

#pragma unroll
    for (int mi = 0; mi < MI; mi++)
#pragma unroll
        for (int ni = 0; ni < 4; ni++)
#pragma unroll
            for (int j = 0; j < 4; j++) {
                const int row = m0 + wr * (MI * 16) + mi * 16 + lq * 4 + j;
                const int col = n0 + wc * 64 + ni * 16 + lr;
                const float v = acc[mi][ni][j];
                if (EPI) {
                    ((float*)Cp)[(size_t)row * N + col] =
                        v + bias[col] + resid[(size_t)row * N + col];
                } else if (TRANSC) {
                    ((u16*)Cp)[((size_t)(col >> 11) * 1280 + row) * 2048 +
                               (col & 2047)] = f2bf(v);
                } else {
                    ((u16*)Cp)[(size_t)row * N + col] = f2bf(v);
                }
            }
}

// ---------------------------------------------------------------------------
// Flash attention. Grid 512 1D (h = id&7 -> XCD-local K/V; bz = (id>>3)&1;
// qt = id>>4, 32 q-rows/block). Block 256 thr = 4 waves = 2 q-groups x
// 2 key-halves of a shared 32-key tile (64 tiles total). Coalesced K/V LDS
// staging (5 x uint4/thread), reg-prefetched one tile ahead. Private online
// softmax (defer-max THR=8, row-sum l via ones MFMA16); 2-way kc merge via
// LDS overlay on dead K region. ~40 KB LDS, no launch_bounds occupancy cap.
// ---------------------------------------------------------------------------
__global__ __launch_bounds__(256) void attn_kernel(
    const u16* __restrict__ qb, const u16* __restrict__ kb,
    const u16* __restrict__ vtb, const int* __restrict__ seg,
    u16* __restrict__ ao) {
    __shared__ __align__(16) u16 arena[20224];
    const int KL = 0;      // K  [32][168] u16  (10752)
    const int VT = 10752;  // Vt [160][40] u16  (6400)
    const int PT = 17152;  // P   4 x [16][28]  (1792)
    const int SG = 18944;  // seg u8[8][256]    (1024 u16)
    const int ML = 19968;  // f32 [4][16][2]    (256 u16)
    u8* segl8 = (u8*)&arena[SG];
    float* Mlf = (float*)&arena[ML];
    float* Osum = (float*)&arena[KL];  // overlay [32][164] f32 (20992B <= 21504B)

    const int tid = threadIdx.x;
    const int lane = tid & 63, w = tid >> 6;
    const int qg = w >> 1, kc = w & 1;
    const int lr = lane & 15, lq = lane >> 4;
    const int id = blockIdx.x;
    const int h = id & 7, bz = (id >> 3) & 1, qt = id >> 4;  // qt 0..31

    // seg rows qt*8 .. +8 as bytes (2048 ints, 8 per thread)
#pragma unroll
    for (int i = 0; i < 2; i++) {
        const int4 v =
            *(const int4*)&seg[(size_t)(bz * 256 + qt * 8) * 256 + tid * 8 + i * 4];
        segl8[tid * 8 + i * 4 + 0] = (u8)v.x;
        segl8[tid * 8 + i * 4 + 1] = (u8)v.y;
        segl8[tid * 8 + i * 4 + 2] = (u8)v.z;
        segl8[tid * 8 + i * 4 + 3] = (u8)v.w;
    }

    // Q fragments (A-operand; wave qg owns q-rows qt*32+qg*16+[0,16))
    bf16x8 qf[5];
    {
        const size_t qrow =
            (size_t)(bz * 1024 + qt * 32 + qg * 16 + lr) * 1280 + h * 160;
#pragma unroll
        for (int ks = 0; ks < 5; ks++)
            qf[ks] = *(const bf16x8*)&qb[qrow + ks * 32 + lq * 8];
    }

    // staging geometry: K 640 chunks (row=n/20, c8=n%20), V 640 (d=n>>2, c=n&3)
    const int nk0 = tid, nk1 = tid + 256;
    const int nv0 = tid, nv1 = tid + 256;
    const bool exK = (tid < 128);
    const int ne = exK ? (512 + tid) : (512 + tid - 128);
    const int gok0 = (nk0 / 20) * 1280 + (nk0 % 20) * 8;
    const int lok0 = (nk0 / 20) * 168 + (nk0 % 20) * 8;
    const int gok1 = (nk1 / 20) * 1280 + (nk1 % 20) * 8;
    const int lok1 = (nk1 / 20) * 168 + (nk1 % 20) * 8;
    const int gov0 = (nv0 >> 2) * 2048 + (nv0 & 3) * 8;
    const int lov0 = (nv0 >> 2) * 40 + (nv0 & 3) * 8;
    const int gov1 = (nv1 >> 2) * 2048 + (nv1 & 3) * 8;
    const int lov1 = (nv1 >> 2) * 40 + (nv1 & 3) * 8;
    const int goe = exK ? ((ne / 20) * 1280 + (ne % 20) * 8)
                        : ((ne >> 2) * 2048 + (ne & 3) * 8);
    const int loe = exK ? ((ne / 20) * 168 + (ne % 20) * 8)
                        : ((ne >> 2) * 40 + (ne & 3) * 8);

    const u16* kT = kb + (size_t)(bz * 2048) * 1280 + h * 160;    // + kt*32*1280
    const u16* vT = vtb + (size_t)(bz * 1280 + h * 160) * 2048;   // + kt*32

    const f32x4 fzero = {0.f, 0.f, 0.f, 0.f};
    f32x4 oacc[10];
#pragma unroll
    for (int d = 0; d < 10; d++) oacc[d] = fzero;
    f32x4 oaccL = fzero;
    float m_i[4] = {0.f, 0.f, 0.f, 0.f};
    const float sc = 0.07905694150420949f;  // 1/sqrt(160)
    const s16x4 ones = {(short)0x3F80, (short)0x3F80, (short)0x3F80, (short)0x3F80};
    u16* ptw = &arena[PT + w * 448];

    // prologue: load tile 0 into regs
    uint4 rk0 = *(const uint4*)&kT[gok0];
    uint4 rk1 = *(const uint4*)&kT[gok1];
    uint4 rv0 = *(const uint4*)&vT[gov0];
    uint4 rv1 = *(const uint4*)&vT[gov1];
    uint4 re  = exK ? *(const uint4*)&kT[goe] : *(const uint4*)&vT[goe];

    for (int kt = 0; kt < 64; kt++) {
        __syncthreads();  // prev tile compute done (kt=0: segl ready after this)
        *(uint4*)&arena[KL + lok0] = rk0;
        *(uint4*)&arena[KL + lok1] = rk1;
        *(uint4*)&arena[VT + lov0] = rv0;
        *(uint4*)&arena[VT + lov1] = rv1;
        if (exK) *(uint4*)&arena[KL + loe] = re;
        else     *(uint4*)&arena[VT + loe] = re;
        if (kt + 1 < 64) {  // prefetch next tile (flies during compute)
            const u16* kTn = kT + (size_t)(kt + 1) * 40960;
            const u16* vTn = vT + (kt + 1) * 32;
            rk0 = *(const uint4*)&kTn[gok0];
            rk1 = *(const uint4*)&kTn[gok1];
            rv0 = *(const uint4*)&vTn[gov0];
            rv1 = *(const uint4*)&vTn[gov1];
            re  = exK ? *(const uint4*)&kTn[goe] : *(const uint4*)&vTn[goe];
        }
        __syncthreads();  // tile visible

        // --- QK^T: 16 q-rows x 16 keys (this wave's kc half) ---
        f32x4 s4 = fzero;
#pragma unroll
        for (int ks = 0; ks < 5; ks++) {
            const bf16x8 bk =
                *(const bf16x8*)&arena[KL + (kc * 16 + lr) * 168 + ks * 32 + lq * 8];
            s4 = MFMA(qf[ks], bk, s4);
        }
        float msk = 0.f;
        if (kt >= 32) {
            const int sg = (kt - 32) * 8 + kc * 4 + (lr >> 2);
            msk = segl8[(qg * 4 + lq) * 256 + sg] ? 0.f : -1e30f;
        }
#pragma unroll
        for (int j = 0; j < 4; j++) s4[j] = s4[j] * sc + msk;

        // defer-max on unreduced scores (THR=8); rescale branch ~never taken
        const bool ex = (s4[0] > m_i[0] + 8.f) || (s4[1] > m_i[1] + 8.f) ||
                        (s4[2] > m_i[2] + 8.f) || (s4[3] > m_i[3] + 8.f);
        if (__any(ex)) {
#pragma unroll
            for (int j = 0; j < 4; j++) {
                float rm = s4[j];
                rm = fmaxf(rm, __shfl_xor(rm, 1));
                rm = fmaxf(rm, __shfl_xor(rm, 2));
                rm = fmaxf(rm, __shfl_xor(rm, 4));
                rm = fmaxf(rm, __shfl_xor(rm, 8));
                const float mn = fmaxf(m_i[j], rm);
                const float al = __expf(m_i[j] - mn);
#pragma unroll
                for (int d = 0; d < 10; d++) oacc[d][j] *= al;
                oaccL[j] *= al;
                m_i[j] = mn;
            }
        }
        // exp + P -> wave-private LDS
#pragma unroll
        for (int j = 0; j < 4; j++) {
            const float e = __expf(s4[j] - m_i[j]);
            ptw[(lq * 4 + j) * 28 + lr] = f2bf(e);
        }
        // PV (A = P, B = V^T-as-B; D[row=q][col=d]); l via ones column
        const s16x4 pa = *(const s16x4*)&ptw[lr * 28 + lq * 4];
        oaccL = MFMA16(pa, ones, oaccL);
#pragma unroll
        for (int nt2 = 0; nt2 < 10; nt2++) {
            const s16x4 bv =
                *(const s16x4*)&arena[VT + (nt2 * 16 + lr) * 40 + kc * 16 + lq * 4];
            oacc[nt2] = MFMA16(pa, bv, oacc[nt2]);
        }
    }

    // ---- 2-way kc merge through LDS overlay ----
    if (lr == 0) {
#pragma unroll
        for (int j = 0; j < 4; j++) {
            Mlf[(w * 16 + lq * 4 + j) * 2 + 0] = m_i[j];
            Mlf[(w * 16 + lq * 4 + j) * 2 + 1] = oaccL[j];
        }
    }
    __syncthreads();
    float aj[4], inv[4];
#pragma unroll
    for (int j = 0; j < 4; j++) {
        const int row = lq * 4 + j;
        const float m1 = Mlf[((w ^ 1) * 16 + row) * 2];
        const float l1 = Mlf[((w ^ 1) * 16 + row) * 2 + 1];
        const float M = fmaxf(m_i[j], m1);
        aj[j] = __expf(m_i[j] - M);
        inv[j] = 1.f / (oaccL[j] * aj[j] + l1 * __expf(m1 - M));
    }
    if (kc == 1) {
#pragma unroll
        for (int nt2 = 0; nt2 < 10; nt2++)
#pragma unroll
            for (int j = 0; j < 4; j++)
                Osum[(qg * 16 + lq * 4 + j) * 164 + nt2 * 16 + lr] =
                    oacc[nt2][j] * aj[j];
    }
    __syncthreads();
    if (kc == 0) {
#pragma unroll
        for (int nt2 = 0; nt2 < 10; nt2++)
#pragma unroll
            for (int j = 0; j < 4; j++) {
                const int row = lq * 4 + j;
                const float v = (oacc[nt2][j] * aj[j] +
                                 Osum[(qg * 16 + row) * 164 + nt2 * 16 + lr]) *
                                inv[j];
                ao[(size_t)(bz * 1024 + qt * 32 + qg * 16 + row) * 1280 + h * 160 +
                   nt2 * 16 + lr] = f2bf(v);
            }
    }
}

// ---------------------------------------------------------------------------
extern "C" void kernel_launch(void* const* d_in, const int* in_sizes, int n_in,
                              void* d_out, int out_size, void* d_ws, size_t ws_size,
                              hipStream_t stream) {
    const float* hs  = (const float*)d_in[0];
    const float* ehs = (const float*)d_in[1];
    const int*   seg = (const int*)d_in[2];
    const float* Wq  = (const float*)d_in[3];
    const float* Wk  = (const float*)d_in[4];
    const float* Wv  = (const float*)d_in[5];
    const float* Wo  = (const float*)d_in[6];
    const float* bo  = (const float*)d_in[7];
    float* out = (float*)d_out;

    u16* base  = (u16*)d_ws;
    u16* WoT   = base;                  // 1,638,400
    u16* qbuf  = WoT + 1638400;         // 2,621,440
    u16* kbuf  = qbuf + 2621440;        // 5,242,880
    u16* vtbuf = kbuf + 5242880;        // 5,242,880
    u16* hbuf  = vtbuf + 5242880;       // 2,621,440 (= aobuf after attn)
    u16* ebuf  = hbuf + 2621440;        // 5,242,880
    u16* WqT   = ebuf + 5242880;        // 1,638,400
    u16* WkT   = WqT + 1638400;         // 1,638,400
    u16* WvT   = WkT + 1638400;         // 1,638,400
    u16* aobuf = hbuf;

    dim3 tb(32, 8), tg(40, 40, 4);
    wtrans_kernel<<<tg, tb, 0, stream>>>(Wq, Wk, Wv, Wo, WqT, WkT, WvT, WoT);
    conv_kernel<<<1280, 256, 0, stream>>>(hs, hbuf, 327680);
    conv_kernel<<<2560, 256, 0, stream>>>(ehs, ebuf, 655360);

    gemm2_kernel<2, false, false><<<dim3(10, 32), 256, 0, stream>>>(
        hbuf, WqT, qbuf, nullptr, nullptr, 2048, 1280, 1280);
    gemm2_kernel<4, false, false><<<dim3(10, 32), 256, 0, stream>>>(
        ebuf, WkT, kbuf, nullptr, nullptr, 4096, 1280, 1280);
    gemm2_kernel<4, true, false><<<dim3(32, 10), 256, 0, stream>>>(
        WvT, ebuf, vtbuf, nullptr, nullptr, 1280, 4096, 1280);

    attn_kernel<<<512, 256, 0, stream>>>(qbuf, kbuf, vtbuf, seg, aobuf);

    gemm2_kernel<2, false, true><<<dim3(10, 32), 256, 0, stream>>>(
        aobuf, WoT, out, bo, hs, 2048, 1280, 1280);
}